// Round 1
// baseline (355.801 us; speedup 1.0000x reference)
//
#include <hip/hip_runtime.h>
#include <math.h>

// Problem constants (from reference setup_inputs)
#define N_EDGES   150000
#define TOTAL     (2 * N_EDGES)   // 300000 scored edges (pos + neg)
#define EMBED_DIM 512
#define WAVES_PER_BLOCK 4
#define BLOCK_THREADS   256
#define N_BLOCKS  ((TOTAL + WAVES_PER_BLOCK - 1) / WAVES_PER_BLOCK)  // 75000

// One wave (64 lanes) per edge: gather two 2KB rows, dot, softplus/BCE.
// Block writes one fp32 partial (sum of its 4 edges' losses) to partials[].
__global__ __launch_bounds__(BLOCK_THREADS) void edge_loss_kernel(
    const float* __restrict__ emb,
    const int*   __restrict__ pos_edges,   // [2, N_EDGES] row-major
    const int*   __restrict__ neg_edges,   // [2, N_EDGES] row-major
    float*       __restrict__ partials)    // [N_BLOCKS]
{
    const int wave = threadIdx.x >> 6;
    const int lane = threadIdx.x & 63;
    const long long gwave = (long long)blockIdx.x * WAVES_PER_BLOCK + wave;

    float per_elem = 0.0f;
    if (gwave < TOTAL) {
        // First N_EDGES waves -> positive edges (label 1), rest -> negative (label 0)
        const int   is_pos = (gwave < N_EDGES);
        const int   e      = is_pos ? (int)gwave : (int)(gwave - N_EDGES);
        const int* __restrict__ edges = is_pos ? pos_edges : neg_edges;
        const float label = is_pos ? 1.0f : 0.0f;

        const int s = edges[e];            // wave-uniform -> scalar load
        const int t = edges[N_EDGES + e];

        const float4* __restrict__ rowA = (const float4*)(emb + (long long)s * EMBED_DIM);
        const float4* __restrict__ rowB = (const float4*)(emb + (long long)t * EMBED_DIM);

        // 512 floats / 64 lanes = 8 floats/lane = 2 float4/lane, coalesced:
        // lanes read float4[0..63] then float4[64..127] of each row.
        float4 a0 = rowA[lane];
        float4 b0 = rowB[lane];
        float4 a1 = rowA[lane + 64];
        float4 b1 = rowB[lane + 64];

        float p = a0.x * b0.x + a0.y * b0.y + a0.z * b0.z + a0.w * b0.w
                + a1.x * b1.x + a1.y * b1.y + a1.z * b1.z + a1.w * b1.w;

        // Wave-64 tree reduction
        #pragma unroll
        for (int off = 32; off > 0; off >>= 1)
            p += __shfl_down(p, off, 64);

        if (lane == 0) {
            const float sc = p;
            // logaddexp(0, sc) = max(sc,0) + log1p(exp(-|sc|))  (stable softplus)
            const float sp = fmaxf(sc, 0.0f) + log1pf(expf(-fabsf(sc)));
            per_elem = sp - sc * label;
        }
    }

    __shared__ float ls[WAVES_PER_BLOCK];
    if (lane == 0) ls[wave] = per_elem;
    __syncthreads();
    if (threadIdx.x == 0) {
        float s = 0.0f;
        #pragma unroll
        for (int i = 0; i < WAVES_PER_BLOCK; i++) s += ls[i];
        partials[blockIdx.x] = s;
    }
}

// Single-block final reduction: fp64 accumulate 75000 partials, write mean.
__global__ __launch_bounds__(BLOCK_THREADS) void reduce_kernel(
    const float* __restrict__ partials, int n, float* __restrict__ out)
{
    double acc = 0.0;
    for (int i = threadIdx.x; i < n; i += BLOCK_THREADS)
        acc += (double)partials[i];

    __shared__ double sh[BLOCK_THREADS];
    sh[threadIdx.x] = acc;
    __syncthreads();
    #pragma unroll
    for (int s = BLOCK_THREADS / 2; s > 0; s >>= 1) {
        if (threadIdx.x < s) sh[threadIdx.x] += sh[threadIdx.x + s];
        __syncthreads();
    }
    if (threadIdx.x == 0)
        out[0] = (float)(sh[0] / (double)TOTAL);
}

extern "C" void kernel_launch(void* const* d_in, const int* in_sizes, int n_in,
                              void* d_out, int out_size, void* d_ws, size_t ws_size,
                              hipStream_t stream) {
    const float* emb = (const float*)d_in[0];  // [50000, 512] fp32
    const int*   pos = (const int*)d_in[1];    // [2, 150000] int32
    const int*   neg = (const int*)d_in[2];    // [2, 150000] int32
    // d_in[3] = num_nodes (unused)
    float* out      = (float*)d_out;
    float* partials = (float*)d_ws;            // 75000 floats = 300 KB scratch

    edge_loss_kernel<<<N_BLOCKS, BLOCK_THREADS, 0, stream>>>(emb, pos, neg, partials);
    reduce_kernel<<<1, BLOCK_THREADS, 0, stream>>>(partials, N_BLOCKS, out);
}